// Round 6
// baseline (342.111 us; speedup 1.0000x reference)
//
#include <hip/hip_runtime.h>

#define N_NODES 50000
#define NIN 512
#define NH 96
#define NL 32
#define NH2 64
#define NC1 24   // float4 chunks per 96-wide row
#define NC2 16   // float4 chunks per 64-wide row

#define SCAN_BLK 49          // blocks in phase 1/3; each covers 1024 elements

__global__ void k_zero_int(int* __restrict__ p, int n) {
    int i = blockIdx.x * blockDim.x + threadIdx.x;
    if (i < n) p[i] = 0;
}

__global__ void k_degi(const int* __restrict__ dst, int* __restrict__ degi, int E) {
    int i = blockIdx.x * blockDim.x + threadIdx.x;
    if (i < E) atomicAdd(&degi[dst[i]], 1);
}

// phase 1: per-block sums of degi (1024 elems/block via int4)
__global__ __launch_bounds__(256) void k_scan1(const int* __restrict__ degi,
                                               int* __restrict__ bsum) {
    __shared__ int red[256];
    int t = threadIdx.x;
    int q = blockIdx.x * 256 + t;
    int s = 0;
    if (q * 4 + 3 < N_NODES) {
        int4 v = reinterpret_cast<const int4*>(degi)[q];
        s = v.x + v.y + v.z + v.w;
    } else {
        for (int j = q * 4; j < min(q * 4 + 4, N_NODES); j++) s += degi[j];
    }
    red[t] = s;
    __syncthreads();
    for (int off = 128; off > 0; off >>= 1) {
        if (t < off) red[t] += red[t + off];
        __syncthreads();
    }
    if (t == 0) bsum[blockIdx.x] = red[0];
}

// phase 2: one wave exclusive-scans the 49 block sums
__global__ __launch_bounds__(64) void k_scan2(const int* __restrict__ bsum,
                                              int* __restrict__ boff) {
    int lane = threadIdx.x;
    int v = (lane < SCAN_BLK) ? bsum[lane] : 0;
    int orig = v;
    for (int off = 1; off < 64; off <<= 1) {
        int w = __shfl_up(v, off, 64);
        if (lane >= off) v += w;
    }
    if (lane < SCAN_BLK) boff[lane] = v - orig;
}

// phase 3: block-local exclusive scan + boff, emit rowoff/dis/cur (+ rowoff[N])
__global__ __launch_bounds__(256) void k_scan3(const int* __restrict__ degi,
                                               const int* __restrict__ boff,
                                               int* __restrict__ rowoff,
                                               int* __restrict__ cur,
                                               float* __restrict__ dis) {
    __shared__ int sums[256];
    int t = threadIdx.x;
    int q = blockIdx.x * 256 + t;
    int d[4] = {0, 0, 0, 0};
    if (q * 4 + 3 < N_NODES) {
        int4 v = reinterpret_cast<const int4*>(degi)[q];
        d[0] = v.x; d[1] = v.y; d[2] = v.z; d[3] = v.w;
    } else {
        for (int j = 0; j < 4; j++)
            if (q * 4 + j < N_NODES) d[j] = degi[q * 4 + j];
    }
    int tsum = d[0] + d[1] + d[2] + d[3];
    sums[t] = tsum;
    __syncthreads();
    for (int off = 1; off < 256; off <<= 1) {
        int v = (t >= off) ? sums[t - off] : 0;
        __syncthreads();
        sums[t] += v;
        __syncthreads();
    }
    int run = boff[blockIdx.x] + sums[t] - tsum;
#pragma unroll
    for (int j = 0; j < 4; j++) {
        int i = q * 4 + j;
        if (i < N_NODES) {
            rowoff[i] = run;
            dis[i] = rsqrtf((float)d[j] + 1.0f);
            cur[i] = 0;
            run += d[j];
            if (i == N_NODES - 1) rowoff[N_NODES] = run;
        }
    }
}

// counting-sort bucket pass: epack = {src_bits, norm} in dst-sorted order
__global__ void k_bucket(const int* __restrict__ src, const int* __restrict__ dst,
                         const int* __restrict__ rowoff, int* __restrict__ cur,
                         const float* __restrict__ dis, float2* __restrict__ epack,
                         int E) {
    int e = blockIdx.x * blockDim.x + threadIdx.x;
    if (e >= E) return;
    int s = src[e], d = dst[e];
    int pos = rowoff[d] + atomicAdd(&cur[d], 1);
    epack[pos] = make_float2(__int_as_float(s), dis[s] * dis[d]);
}

// h = x @ W1   [N,512] @ [512,96] -> [N,96]
// BM=128 rows, 128 threads (16 tr x 8 tc), 8x12 register tile.
// Per k: 2x ds_read_b128 (A, interleaved layout -> dense, conflict-free) +
// 3x ds_read_b128 (B, 4-distinct-addr broadcast) feeding 96 FMAs -> VALU-bound.
#define BM1 128
#define BK1 32
// interleaved column mapping for the transposed x tile (see round-5 notes):
// rows tr*8+0..3 -> cols tr*4+0..3 ; rows tr*8+4..7 -> cols 64+tr*4+0..3
__device__ __forceinline__ int xcol(int r) {
    return ((r >> 3) << 2) + (r & 3) + ((r & 4) << 4);
}

__global__ __launch_bounds__(128) void k_gemm1(const float* __restrict__ x,
                                               const float* __restrict__ W,
                                               float* __restrict__ h, int M) {
    __shared__ float xs[BK1][BM1 + 4];   // 32 x 132 (stride 528B -> 4-bank rotate/row)
    __shared__ float ws[BK1][NH];        // 32 x 96
    int tid = threadIdx.x;
    int m0 = blockIdx.x * BM1;
    int tr = tid & 15, tc = tid >> 4;    // 16 row-groups x 8 col-groups

    float acc[8][12];
#pragma unroll
    for (int i = 0; i < 8; i++)
#pragma unroll
        for (int j = 0; j < 12; j++) acc[i][j] = 0.f;

    float4 gx[8], gw[6];

    // ---- stage tile 0 into regs ----
#pragma unroll
    for (int it = 0; it < 8; ++it) {
        int idx = it * 128 + tid;          // 0..1023
        int r = idx >> 3, c4 = idx & 7;    // 128 rows x 8 quads
        int gr = m0 + r;
        gx[it] = (gr < M) ? *reinterpret_cast<const float4*>(&x[(size_t)gr * NIN + c4 * 4])
                          : make_float4(0.f, 0.f, 0.f, 0.f);
    }
#pragma unroll
    for (int it = 0; it < 6; ++it) {
        int idx = it * 128 + tid;          // 0..767
        int r = idx / 24, c4 = idx % 24;
        gw[it] = *reinterpret_cast<const float4*>(&W[(size_t)r * NH + c4 * 4]);
    }

    for (int t = 0; t < NIN / BK1; ++t) {
        __syncthreads();
#pragma unroll
        for (int it = 0; it < 8; ++it) {
            int idx = it * 128 + tid;
            int r = idx >> 3, c4 = idx & 7;
            int cc = xcol(r);
            xs[c4 * 4 + 0][cc] = gx[it].x;
            xs[c4 * 4 + 1][cc] = gx[it].y;
            xs[c4 * 4 + 2][cc] = gx[it].z;
            xs[c4 * 4 + 3][cc] = gx[it].w;
        }
#pragma unroll
        for (int it = 0; it < 6; ++it) {
            int idx = it * 128 + tid;
            int r = idx / 24, c4 = idx % 24;
            *reinterpret_cast<float4*>(&ws[r][c4 * 4]) = gw[it];
        }
        __syncthreads();

        if (t + 1 < NIN / BK1) {
            int k0 = (t + 1) * BK1;
#pragma unroll
            for (int it = 0; it < 8; ++it) {
                int idx = it * 128 + tid;
                int r = idx >> 3, c4 = idx & 7;
                int gr = m0 + r;
                gx[it] = (gr < M) ? *reinterpret_cast<const float4*>(&x[(size_t)gr * NIN + k0 + c4 * 4])
                                  : make_float4(0.f, 0.f, 0.f, 0.f);
            }
#pragma unroll
            for (int it = 0; it < 6; ++it) {
                int idx = it * 128 + tid;
                int r = idx / 24, c4 = idx % 24;
                gw[it] = *reinterpret_cast<const float4*>(&W[(size_t)(k0 + r) * NH + c4 * 4]);
            }
        }

#pragma unroll 4
        for (int k = 0; k < BK1; k++) {
            float4 a0 = *reinterpret_cast<const float4*>(&xs[k][tr * 4]);
            float4 a1 = *reinterpret_cast<const float4*>(&xs[k][64 + tr * 4]);
            float4 b0 = *reinterpret_cast<const float4*>(&ws[k][tc * 12]);
            float4 b1 = *reinterpret_cast<const float4*>(&ws[k][tc * 12 + 4]);
            float4 b2 = *reinterpret_cast<const float4*>(&ws[k][tc * 12 + 8]);
            float av[8] = {a0.x, a0.y, a0.z, a0.w, a1.x, a1.y, a1.z, a1.w};
            float bv[12] = {b0.x, b0.y, b0.z, b0.w, b1.x, b1.y, b1.z, b1.w,
                            b2.x, b2.y, b2.z, b2.w};
#pragma unroll
            for (int i = 0; i < 8; i++)
#pragma unroll
                for (int j = 0; j < 12; j++) acc[i][j] = fmaf(av[i], bv[j], acc[i][j]);
        }
    }

#pragma unroll
    for (int i = 0; i < 8; i++) {
        int gr = m0 + tr * 8 + i;
        if (gr < M) {
            float* hp = &h[(size_t)gr * NH + tc * 12];
#pragma unroll
            for (int q = 0; q < 3; q++)
                *reinterpret_cast<float4*>(hp + q * 4) =
                    make_float4(acc[i][q * 4], acc[i][q * 4 + 1],
                                acc[i][q * 4 + 2], acc[i][q * 4 + 3]);
        }
    }
}

// gather-side aggregation layer 1, fused self-loop + bias + relu.
__global__ __launch_bounds__(256) void k_gather1(const float4* __restrict__ h4,
                                                 const int* __restrict__ rowoff,
                                                 const float2* __restrict__ epack,
                                                 const float* __restrict__ dis,
                                                 const float* __restrict__ b1,
                                                 float4* __restrict__ hid4) {
    int tid = threadIdx.x;
    int node = blockIdx.x * 8 + (tid >> 5);
    int c = tid & 31;
    if (node >= N_NODES) return;
    int p0 = rowoff[node], p1 = rowoff[node + 1];
    bool act = (c < NC1);
    float4 acc = make_float4(0.f, 0.f, 0.f, 0.f);
    for (int pb = p0; pb < p1; pb += NC1) {
        int nb = min(NC1, p1 - pb);
        float2 ev = make_float2(0.f, 0.f);
        if (c < nb) ev = epack[pb + c];
#pragma unroll 4
        for (int j = 0; j < nb; j++) {
            int s = __float_as_int(__shfl(ev.x, j, 32));
            float w = __shfl(ev.y, j, 32);
            if (act) {
                float4 v = h4[(size_t)s * NC1 + c];
                acc.x = fmaf(v.x, w, acc.x);
                acc.y = fmaf(v.y, w, acc.y);
                acc.z = fmaf(v.z, w, acc.z);
                acc.w = fmaf(v.w, w, acc.w);
            }
        }
    }
    if (act) {
        float dv = dis[node];
        float sw = dv * dv;
        float4 hv = h4[(size_t)node * NC1 + c];
        float4 bv = *reinterpret_cast<const float4*>(&b1[c * 4]);
        acc.x = fmaxf(fmaf(hv.x, sw, acc.x) + bv.x, 0.f);
        acc.y = fmaxf(fmaf(hv.y, sw, acc.y) + bv.y, 0.f);
        acc.z = fmaxf(fmaf(hv.z, sw, acc.z) + bv.z, 0.f);
        acc.w = fmaxf(fmaf(hv.w, sw, acc.w) + bv.w, 0.f);
        hid4[(size_t)node * NC1 + c] = acc;
    }
}

// h23 = hidden @ [W_mu | W_logstd]   [N,96] @ [96,64] -> [N,64]
__global__ __launch_bounds__(256) void k_gemm2(const float* __restrict__ hid,
                                               const float* __restrict__ Wmu,
                                               const float* __restrict__ Wls,
                                               float* __restrict__ h23, int M) {
    __shared__ float wl[NH][NH2];
    int tid = threadIdx.x;
#pragma unroll
    for (int it = 0; it < 6; ++it) {
        int idx = it * 256 + tid;
        int k = idx >> 4;
        int c4 = idx & 15;
        float4 v;
        if (c4 < 8) v = *reinterpret_cast<const float4*>(&Wmu[k * NL + c4 * 4]);
        else        v = *reinterpret_cast<const float4*>(&Wls[k * NL + (c4 - 8) * 4]);
        *reinterpret_cast<float4*>(&wl[k][c4 * 4]) = v;
    }
    __syncthreads();
    int row = blockIdx.x * 128 + (tid >> 1);
    int half = tid & 1;
    if (row >= M) return;
    float acc[NL];
#pragma unroll
    for (int j = 0; j < NL; j++) acc[j] = 0.f;
    const float4* hr4 = reinterpret_cast<const float4*>(&hid[(size_t)row * NH]);
#pragma unroll 6
    for (int kq = 0; kq < NH / 4; kq++) {
        float4 hv = hr4[kq];
        float hvv[4] = {hv.x, hv.y, hv.z, hv.w};
#pragma unroll
        for (int kk = 0; kk < 4; kk++) {
            const float* w = &wl[kq * 4 + kk][half * NL];
#pragma unroll
            for (int j = 0; j < NL; j++) acc[j] = fmaf(hvv[kk], w[j], acc[j]);
        }
    }
    float4* o4 = reinterpret_cast<float4*>(&h23[(size_t)row * NH2 + half * NL]);
#pragma unroll
    for (int j4 = 0; j4 < 8; j4++)
        o4[j4] = make_float4(acc[j4 * 4], acc[j4 * 4 + 1], acc[j4 * 4 + 2], acc[j4 * 4 + 3]);
}

// gather-side aggregation layer 2, fused self-loop + bias + mu/logstd split.
__global__ __launch_bounds__(256) void k_gather2(const float4* __restrict__ h23_4,
                                                 const int* __restrict__ rowoff,
                                                 const float2* __restrict__ epack,
                                                 const float* __restrict__ dis,
                                                 const float* __restrict__ bmu,
                                                 const float* __restrict__ bls,
                                                 float4* __restrict__ out4) {
    int tid = threadIdx.x;
    int node = blockIdx.x * 16 + (tid >> 4);
    int c = tid & 15;
    if (node >= N_NODES) return;
    int p0 = rowoff[node], p1 = rowoff[node + 1];
    float4 acc = make_float4(0.f, 0.f, 0.f, 0.f);
    for (int pb = p0; pb < p1; pb += NC2) {
        int nb = min(NC2, p1 - pb);
        float2 ev = make_float2(0.f, 0.f);
        if (c < nb) ev = epack[pb + c];
#pragma unroll 4
        for (int j = 0; j < nb; j++) {
            int s = __float_as_int(__shfl(ev.x, j, 16));
            float w = __shfl(ev.y, j, 16);
            float4 v = h23_4[(size_t)s * NC2 + c];
            acc.x = fmaf(v.x, w, acc.x);
            acc.y = fmaf(v.y, w, acc.y);
            acc.z = fmaf(v.z, w, acc.z);
            acc.w = fmaf(v.w, w, acc.w);
        }
    }
    float dv = dis[node];
    float sw = dv * dv;
    float4 hv = h23_4[(size_t)node * NC2 + c];
    float4 bv = (c < 8) ? reinterpret_cast<const float4*>(bmu)[c]
                        : reinterpret_cast<const float4*>(bls)[c - 8];
    acc.x = fmaf(hv.x, sw, acc.x) + bv.x;
    acc.y = fmaf(hv.y, sw, acc.y) + bv.y;
    acc.z = fmaf(hv.z, sw, acc.z) + bv.z;
    acc.w = fmaf(hv.w, sw, acc.w) + bv.w;
    if (c < 8) out4[(size_t)node * 8 + c] = acc;
    else       out4[(size_t)N_NODES * 8 + (size_t)node * 8 + (c - 8)] = acc;
}

extern "C" void kernel_launch(void* const* d_in, const int* in_sizes, int n_in,
                              void* d_out, int out_size, void* d_ws, size_t ws_size,
                              hipStream_t stream) {
    const float* x   = (const float*)d_in[0];
    const float* W1  = (const float*)d_in[1];
    const float* b1  = (const float*)d_in[2];
    const float* Wmu = (const float*)d_in[3];
    const float* bmu = (const float*)d_in[4];
    const float* Wls = (const float*)d_in[5];
    const float* bls = (const float*)d_in[6];
    const int*   ei  = (const int*)d_in[7];
    int E = in_sizes[7] / 2;
    const int* src  = ei;
    const int* dstp = ei + E;

    char* w = (char*)d_ws;
    int* degi    = (int*)w;     w += (size_t)N_NODES * 4;
    int* cur     = (int*)w;     w += (size_t)N_NODES * 4;
    int* rowoff  = (int*)w;     w += ((size_t)N_NODES + 4) * 4;
    float* dis   = (float*)w;   w += (size_t)N_NODES * 4;
    int* bsum    = (int*)w;     w += 64 * 4;
    int* boff    = (int*)w;     w += 64 * 4;
    float2* epack= (float2*)w;  w += (size_t)E * 8;
    float* h     = (float*)w;   w += (size_t)N_NODES * NH * 4;
    float* hid   = (float*)w;   w += (size_t)N_NODES * NH * 4;
    float* h23   = (float*)w;   w += (size_t)N_NODES * NH2 * 4;

    k_zero_int<<<(N_NODES + 255) / 256, 256, 0, stream>>>(degi, N_NODES);
    k_degi<<<(E + 255) / 256, 256, 0, stream>>>(dstp, degi, E);
    k_scan1<<<SCAN_BLK, 256, 0, stream>>>(degi, bsum);
    k_scan2<<<1, 64, 0, stream>>>(bsum, boff);
    k_scan3<<<SCAN_BLK, 256, 0, stream>>>(degi, boff, rowoff, cur, dis);
    k_bucket<<<(E + 255) / 256, 256, 0, stream>>>(src, dstp, rowoff, cur, dis, epack, E);

    k_gemm1<<<(N_NODES + BM1 - 1) / BM1, 128, 0, stream>>>(x, W1, h, N_NODES);

    k_gather1<<<(N_NODES + 7) / 8, 256, 0, stream>>>(
        (const float4*)h, rowoff, epack, dis, b1, (float4*)hid);

    k_gemm2<<<(N_NODES + 127) / 128, 256, 0, stream>>>(hid, Wmu, Wls, h23, N_NODES);

    k_gather2<<<(N_NODES + 15) / 16, 256, 0, stream>>>(
        (const float4*)h23, rowoff, epack, dis, bmu, bls, (float4*)d_out);
}

// Round 7
// 301.829 us; speedup vs baseline: 1.1335x; 1.1335x over previous
//
#include <hip/hip_runtime.h>

#define N_NODES 50000
#define NIN 512
#define NH 96
#define NL 32
#define NH2 64
#define NC1 24   // float4 chunks per 96-wide row
#define NC2 16   // float4 chunks per 64-wide row

#define SCAN_BLK 49

__global__ void k_zero_int(int* __restrict__ p, int n) {
    int i = blockIdx.x * blockDim.x + threadIdx.x;
    if (i < n) p[i] = 0;
}

__global__ void k_degi(const int* __restrict__ dst, int* __restrict__ degi, int E) {
    int i = blockIdx.x * blockDim.x + threadIdx.x;
    if (i < E) atomicAdd(&degi[dst[i]], 1);
}

__global__ __launch_bounds__(256) void k_scan1(const int* __restrict__ degi,
                                               int* __restrict__ bsum) {
    __shared__ int red[256];
    int t = threadIdx.x;
    int q = blockIdx.x * 256 + t;
    int s = 0;
    if (q * 4 + 3 < N_NODES) {
        int4 v = reinterpret_cast<const int4*>(degi)[q];
        s = v.x + v.y + v.z + v.w;
    } else {
        for (int j = q * 4; j < min(q * 4 + 4, N_NODES); j++) s += degi[j];
    }
    red[t] = s;
    __syncthreads();
    for (int off = 128; off > 0; off >>= 1) {
        if (t < off) red[t] += red[t + off];
        __syncthreads();
    }
    if (t == 0) bsum[blockIdx.x] = red[0];
}

__global__ __launch_bounds__(64) void k_scan2(const int* __restrict__ bsum,
                                              int* __restrict__ boff) {
    int lane = threadIdx.x;
    int v = (lane < SCAN_BLK) ? bsum[lane] : 0;
    int orig = v;
    for (int off = 1; off < 64; off <<= 1) {
        int w = __shfl_up(v, off, 64);
        if (lane >= off) v += w;
    }
    if (lane < SCAN_BLK) boff[lane] = v - orig;
}

__global__ __launch_bounds__(256) void k_scan3(const int* __restrict__ degi,
                                               const int* __restrict__ boff,
                                               int* __restrict__ rowoff,
                                               int* __restrict__ cur,
                                               float* __restrict__ dis) {
    __shared__ int sums[256];
    int t = threadIdx.x;
    int q = blockIdx.x * 256 + t;
    int d[4] = {0, 0, 0, 0};
    if (q * 4 + 3 < N_NODES) {
        int4 v = reinterpret_cast<const int4*>(degi)[q];
        d[0] = v.x; d[1] = v.y; d[2] = v.z; d[3] = v.w;
    } else {
        for (int j = 0; j < 4; j++)
            if (q * 4 + j < N_NODES) d[j] = degi[q * 4 + j];
    }
    int tsum = d[0] + d[1] + d[2] + d[3];
    sums[t] = tsum;
    __syncthreads();
    for (int off = 1; off < 256; off <<= 1) {
        int v = (t >= off) ? sums[t - off] : 0;
        __syncthreads();
        sums[t] += v;
        __syncthreads();
    }
    int run = boff[blockIdx.x] + sums[t] - tsum;
#pragma unroll
    for (int j = 0; j < 4; j++) {
        int i = q * 4 + j;
        if (i < N_NODES) {
            rowoff[i] = run;
            dis[i] = rsqrtf((float)d[j] + 1.0f);
            cur[i] = 0;
            run += d[j];
            if (i == N_NODES - 1) rowoff[N_NODES] = run;
        }
    }
}

// counting-sort bucket pass: esrc in dst-sorted order (weights folded into h')
__global__ void k_bucket(const int* __restrict__ src, const int* __restrict__ dst,
                         const int* __restrict__ rowoff, int* __restrict__ cur,
                         int* __restrict__ esrc, int E) {
    int e = blockIdx.x * blockDim.x + threadIdx.x;
    if (e >= E) return;
    int s = src[e], d = dst[e];
    int pos = rowoff[d] + atomicAdd(&cur[d], 1);
    esrc[pos] = s;
}

// h_part[ks] = x[:, ks*256:(ks+1)*256] @ W1[ks*256:(ks+1)*256, :]
// BM=128 rows, 256 threads (32 tr x 8 tc), 4x12 register tile, split-K=2 via blockIdx.y.
// A-read: 1x ds_read_b128 dense (2-way mirror = free); B-read: 3x b128, 32-lane
// same-address broadcast (free). 48 FMA per 4 DS insts -> ~issue-balanced.
#define BM1 128
#define BK1 32
#define KS 2
#define KSL (NIN / KS)        // 256 k per slice
__global__ __launch_bounds__(256) void k_gemm1(const float* __restrict__ x,
                                               const float* __restrict__ W,
                                               float* __restrict__ hpart, int M) {
    __shared__ float xs[BK1][BM1 + 4];   // stride 132 words (528 B, 16B-aligned)
    __shared__ float ws[BK1][NH];
    int tid = threadIdx.x;
    int m0 = blockIdx.x * BM1;
    int ks = blockIdx.y;
    int kbase = ks * KSL;
    int tr = tid & 31, tc = tid >> 5;    // 32 row-groups x 8 col-groups

    float acc[4][12];
#pragma unroll
    for (int i = 0; i < 4; i++)
#pragma unroll
        for (int j = 0; j < 12; j++) acc[i][j] = 0.f;

    float4 gx[4], gw[3];

    // stage tile 0
#pragma unroll
    for (int it = 0; it < 4; ++it) {
        int idx = it * 256 + tid;          // 0..1023
        int r = idx >> 3, c4 = idx & 7;    // 128 rows x 8 quads (32 k)
        int gr = m0 + r;
        gx[it] = (gr < M) ? *reinterpret_cast<const float4*>(&x[(size_t)gr * NIN + kbase + c4 * 4])
                          : make_float4(0.f, 0.f, 0.f, 0.f);
    }
#pragma unroll
    for (int it = 0; it < 3; ++it) {
        int idx = it * 256 + tid;          // 0..767
        int r = idx / 24, c4 = idx % 24;
        gw[it] = *reinterpret_cast<const float4*>(&W[(size_t)(kbase + r) * NH + c4 * 4]);
    }

    for (int t = 0; t < KSL / BK1; ++t) {
        __syncthreads();
#pragma unroll
        for (int it = 0; it < 4; ++it) {
            int idx = it * 256 + tid;
            int r = idx >> 3, c4 = idx & 7;
            xs[c4 * 4 + 0][r] = gx[it].x;
            xs[c4 * 4 + 1][r] = gx[it].y;
            xs[c4 * 4 + 2][r] = gx[it].z;
            xs[c4 * 4 + 3][r] = gx[it].w;
        }
#pragma unroll
        for (int it = 0; it < 3; ++it) {
            int idx = it * 256 + tid;
            int r = idx / 24, c4 = idx % 24;
            *reinterpret_cast<float4*>(&ws[r][c4 * 4]) = gw[it];
        }
        __syncthreads();

        if (t + 1 < KSL / BK1) {
            int k0 = kbase + (t + 1) * BK1;
#pragma unroll
            for (int it = 0; it < 4; ++it) {
                int idx = it * 256 + tid;
                int r = idx >> 3, c4 = idx & 7;
                int gr = m0 + r;
                gx[it] = (gr < M) ? *reinterpret_cast<const float4*>(&x[(size_t)gr * NIN + k0 + c4 * 4])
                                  : make_float4(0.f, 0.f, 0.f, 0.f);
            }
#pragma unroll
            for (int it = 0; it < 3; ++it) {
                int idx = it * 256 + tid;
                int r = idx / 24, c4 = idx % 24;
                gw[it] = *reinterpret_cast<const float4*>(&W[(size_t)(k0 + r) * NH + c4 * 4]);
            }
        }

#pragma unroll 4
        for (int k = 0; k < BK1; k++) {
            float4 a = *reinterpret_cast<const float4*>(&xs[k][tr * 4]);
            float4 b0 = *reinterpret_cast<const float4*>(&ws[k][tc * 12]);
            float4 b1 = *reinterpret_cast<const float4*>(&ws[k][tc * 12 + 4]);
            float4 b2 = *reinterpret_cast<const float4*>(&ws[k][tc * 12 + 8]);
            float av[4] = {a.x, a.y, a.z, a.w};
            float bv[12] = {b0.x, b0.y, b0.z, b0.w, b1.x, b1.y, b1.z, b1.w,
                            b2.x, b2.y, b2.z, b2.w};
#pragma unroll
            for (int i = 0; i < 4; i++)
#pragma unroll
                for (int j = 0; j < 12; j++) acc[i][j] = fmaf(av[i], bv[j], acc[i][j]);
        }
    }

    float* hp = hpart + (size_t)ks * N_NODES * NH;
#pragma unroll
    for (int i = 0; i < 4; i++) {
        int gr = m0 + tr * 4 + i;
        if (gr < M) {
            float* p = hp + (size_t)gr * NH + tc * 12;
#pragma unroll
            for (int q = 0; q < 3; q++)
                *reinterpret_cast<float4*>(p + q * 4) =
                    make_float4(acc[i][q * 4], acc[i][q * 4 + 1],
                                acc[i][q * 4 + 2], acc[i][q * 4 + 3]);
        }
    }
}

// h' = (part0 + part1) * dis[row]   (in place into part0)
__global__ __launch_bounds__(256) void k_reduce(float4* __restrict__ p0,
                                                const float4* __restrict__ p1,
                                                const float* __restrict__ dis, int n4) {
    int i = blockIdx.x * blockDim.x + threadIdx.x;
    if (i >= n4) return;
    float4 a = p0[i], b = p1[i];
    float s = dis[i / NC1];
    p0[i] = make_float4((a.x + b.x) * s, (a.y + b.y) * s,
                        (a.z + b.z) * s, (a.w + b.w) * s);
}

// gather layer 1: hid = relu((sum_{s in N(i)} h'[s] + h'[i]) * dis[i] + b1)
__global__ __launch_bounds__(256) void k_gather1(const float4* __restrict__ h4,
                                                 const int* __restrict__ rowoff,
                                                 const int* __restrict__ esrc,
                                                 const float* __restrict__ dis,
                                                 const float* __restrict__ b1,
                                                 float4* __restrict__ hid4) {
    int tid = threadIdx.x;
    int node = blockIdx.x * 8 + (tid >> 5);
    int c = tid & 31;
    if (node >= N_NODES) return;
    int p0 = rowoff[node], p1 = rowoff[node + 1];
    bool act = (c < NC1);
    float4 acc = make_float4(0.f, 0.f, 0.f, 0.f);
    for (int pb = p0; pb < p1; pb += 32) {
        int nb = min(32, p1 - pb);
        int sv = (c < nb) ? esrc[pb + c] : 0;
#pragma unroll 4
        for (int j = 0; j < nb; j++) {
            int s = __shfl(sv, j, 32);
            if (act) {
                float4 v = h4[(size_t)s * NC1 + c];
                acc.x += v.x; acc.y += v.y; acc.z += v.z; acc.w += v.w;
            }
        }
    }
    if (act) {
        float dv = dis[node];
        float4 hv = h4[(size_t)node * NC1 + c];
        float4 bv = *reinterpret_cast<const float4*>(&b1[c * 4]);
        acc.x = fmaxf((acc.x + hv.x) * dv + bv.x, 0.f);
        acc.y = fmaxf((acc.y + hv.y) * dv + bv.y, 0.f);
        acc.z = fmaxf((acc.z + hv.z) * dv + bv.z, 0.f);
        acc.w = fmaxf((acc.w + hv.w) * dv + bv.w, 0.f);
        hid4[(size_t)node * NC1 + c] = acc;
    }
}

// h23' = (hid @ [W_mu | W_logstd]) * dis[row]
__global__ __launch_bounds__(256) void k_gemm2(const float* __restrict__ hid,
                                               const float* __restrict__ Wmu,
                                               const float* __restrict__ Wls,
                                               const float* __restrict__ dis,
                                               float* __restrict__ h23, int M) {
    __shared__ float wl[NH][NH2];
    int tid = threadIdx.x;
#pragma unroll
    for (int it = 0; it < 6; ++it) {
        int idx = it * 256 + tid;
        int k = idx >> 4;
        int c4 = idx & 15;
        float4 v;
        if (c4 < 8) v = *reinterpret_cast<const float4*>(&Wmu[k * NL + c4 * 4]);
        else        v = *reinterpret_cast<const float4*>(&Wls[k * NL + (c4 - 8) * 4]);
        *reinterpret_cast<float4*>(&wl[k][c4 * 4]) = v;
    }
    __syncthreads();
    int row = blockIdx.x * 128 + (tid >> 1);
    int half = tid & 1;
    if (row >= M) return;
    float acc[NL];
#pragma unroll
    for (int j = 0; j < NL; j++) acc[j] = 0.f;
    const float4* hr4 = reinterpret_cast<const float4*>(&hid[(size_t)row * NH]);
#pragma unroll 6
    for (int kq = 0; kq < NH / 4; kq++) {
        float4 hv = hr4[kq];
        float hvv[4] = {hv.x, hv.y, hv.z, hv.w};
#pragma unroll
        for (int kk = 0; kk < 4; kk++) {
            const float* w = &wl[kq * 4 + kk][half * NL];
#pragma unroll
            for (int j = 0; j < NL; j++) acc[j] = fmaf(hvv[kk], w[j], acc[j]);
        }
    }
    float dv = dis[row];
    float4* o4 = reinterpret_cast<float4*>(&h23[(size_t)row * NH2 + half * NL]);
#pragma unroll
    for (int j4 = 0; j4 < 8; j4++)
        o4[j4] = make_float4(acc[j4 * 4] * dv, acc[j4 * 4 + 1] * dv,
                             acc[j4 * 4 + 2] * dv, acc[j4 * 4 + 3] * dv);
}

// gather layer 2: out = (sum h23'[s] + h23'[i]) * dis[i] + bias, split mu/logstd
__global__ __launch_bounds__(256) void k_gather2(const float4* __restrict__ h23_4,
                                                 const int* __restrict__ rowoff,
                                                 const int* __restrict__ esrc,
                                                 const float* __restrict__ dis,
                                                 const float* __restrict__ bmu,
                                                 const float* __restrict__ bls,
                                                 float4* __restrict__ out4) {
    int tid = threadIdx.x;
    int node = blockIdx.x * 16 + (tid >> 4);
    int c = tid & 15;
    if (node >= N_NODES) return;
    int p0 = rowoff[node], p1 = rowoff[node + 1];
    float4 acc = make_float4(0.f, 0.f, 0.f, 0.f);
    for (int pb = p0; pb < p1; pb += 16) {
        int nb = min(16, p1 - pb);
        int sv = (c < nb) ? esrc[pb + c] : 0;
#pragma unroll 4
        for (int j = 0; j < nb; j++) {
            int s = __shfl(sv, j, 16);
            float4 v = h23_4[(size_t)s * NC2 + c];
            acc.x += v.x; acc.y += v.y; acc.z += v.z; acc.w += v.w;
        }
    }
    float dv = dis[node];
    float4 hv = h23_4[(size_t)node * NC2 + c];
    float4 bv = (c < 8) ? reinterpret_cast<const float4*>(bmu)[c]
                        : reinterpret_cast<const float4*>(bls)[c - 8];
    acc.x = (acc.x + hv.x) * dv + bv.x;
    acc.y = (acc.y + hv.y) * dv + bv.y;
    acc.z = (acc.z + hv.z) * dv + bv.z;
    acc.w = (acc.w + hv.w) * dv + bv.w;
    if (c < 8) out4[(size_t)node * 8 + c] = acc;
    else       out4[(size_t)N_NODES * 8 + (size_t)node * 8 + (c - 8)] = acc;
}

extern "C" void kernel_launch(void* const* d_in, const int* in_sizes, int n_in,
                              void* d_out, int out_size, void* d_ws, size_t ws_size,
                              hipStream_t stream) {
    const float* x   = (const float*)d_in[0];
    const float* W1  = (const float*)d_in[1];
    const float* b1  = (const float*)d_in[2];
    const float* Wmu = (const float*)d_in[3];
    const float* bmu = (const float*)d_in[4];
    const float* Wls = (const float*)d_in[5];
    const float* bls = (const float*)d_in[6];
    const int*   ei  = (const int*)d_in[7];
    int E = in_sizes[7] / 2;
    const int* src  = ei;
    const int* dstp = ei + E;

    char* w = (char*)d_ws;
    int* degi    = (int*)w;     w += (size_t)N_NODES * 4;
    int* cur     = (int*)w;     w += (size_t)N_NODES * 4;
    int* rowoff  = (int*)w;     w += ((size_t)N_NODES + 4) * 4;
    float* dis   = (float*)w;   w += (size_t)N_NODES * 4;
    int* bsum    = (int*)w;     w += 64 * 4;
    int* boff    = (int*)w;     w += 64 * 4;
    int* esrc    = (int*)w;     w += (size_t)E * 4;
    float* hpart = (float*)w;   w += (size_t)KS * N_NODES * NH * 4;  // part0 = h'
    float* hid   = (float*)w;   w += (size_t)N_NODES * NH * 4;
    float* h23   = hpart + (size_t)N_NODES * NH;   // overlay onto part1 (dead after reduce)

    k_zero_int<<<(N_NODES + 255) / 256, 256, 0, stream>>>(degi, N_NODES);
    k_degi<<<(E + 255) / 256, 256, 0, stream>>>(dstp, degi, E);
    k_scan1<<<SCAN_BLK, 256, 0, stream>>>(degi, bsum);
    k_scan2<<<1, 64, 0, stream>>>(bsum, boff);
    k_scan3<<<SCAN_BLK, 256, 0, stream>>>(degi, boff, rowoff, cur, dis);
    k_bucket<<<(E + 255) / 256, 256, 0, stream>>>(src, dstp, rowoff, cur, esrc, E);

    dim3 g1((N_NODES + BM1 - 1) / BM1, KS);
    k_gemm1<<<g1, 256, 0, stream>>>(x, W1, hpart, N_NODES);

    int n4 = N_NODES * NC1;   // 1.2M float4s
    k_reduce<<<(n4 + 255) / 256, 256, 0, stream>>>(
        (float4*)hpart, (const float4*)(hpart + (size_t)N_NODES * NH), dis, n4);

    k_gather1<<<(N_NODES + 7) / 8, 256, 0, stream>>>(
        (const float4*)hpart, rowoff, esrc, dis, b1, (float4*)hid);

    k_gemm2<<<(N_NODES + 127) / 128, 256, 0, stream>>>(hid, Wmu, Wls, dis, h23, N_NODES);

    k_gather2<<<(N_NODES + 15) / 16, 256, 0, stream>>>(
        (const float4*)h23, rowoff, esrc, dis, bmu, bls, (float4*)d_out);
}

// Round 9
// 241.170 us; speedup vs baseline: 1.4186x; 1.2515x over previous
//
#include <hip/hip_runtime.h>

#define N_NODES 50000
#define NIN 512
#define NH 96
#define NL 32
#define NH2 64
#define NC1 24   // float4 chunks per 96-wide row
#define NC2 16   // float4 chunks per 64-wide row

#define SCAN_BLK 49

typedef __attribute__((ext_vector_type(8))) short short8v;   // 8 bf16 (4 VGPR)
typedef __attribute__((ext_vector_type(4))) float f32x4;

__device__ __forceinline__ unsigned short f2bf(float f) {    // RNE f32->bf16
    unsigned u = __float_as_uint(f);
    u = (u + 0x7FFFu + ((u >> 16) & 1u)) >> 16;
    return (unsigned short)u;
}

__global__ void k_zero_int(int* __restrict__ p, int n) {
    int i = blockIdx.x * blockDim.x + threadIdx.x;
    if (i < n) p[i] = 0;
}

__global__ void k_degi(const int* __restrict__ dst, int* __restrict__ degi, int E) {
    int i = blockIdx.x * blockDim.x + threadIdx.x;
    if (i < E) atomicAdd(&degi[dst[i]], 1);
}

__global__ __launch_bounds__(256) void k_scan1(const int* __restrict__ degi,
                                               int* __restrict__ bsum) {
    __shared__ int red[256];
    int t = threadIdx.x;
    int q = blockIdx.x * 256 + t;
    int s = 0;
    if (q * 4 + 3 < N_NODES) {
        int4 v = reinterpret_cast<const int4*>(degi)[q];
        s = v.x + v.y + v.z + v.w;
    } else {
        for (int j = q * 4; j < min(q * 4 + 4, N_NODES); j++) s += degi[j];
    }
    red[t] = s;
    __syncthreads();
    for (int off = 128; off > 0; off >>= 1) {
        if (t < off) red[t] += red[t + off];
        __syncthreads();
    }
    if (t == 0) bsum[blockIdx.x] = red[0];
}

__global__ __launch_bounds__(64) void k_scan2(const int* __restrict__ bsum,
                                              int* __restrict__ boff) {
    int lane = threadIdx.x;
    int v = (lane < SCAN_BLK) ? bsum[lane] : 0;
    int orig = v;
    for (int off = 1; off < 64; off <<= 1) {
        int w = __shfl_up(v, off, 64);
        if (lane >= off) v += w;
    }
    if (lane < SCAN_BLK) boff[lane] = v - orig;
}

__global__ __launch_bounds__(256) void k_scan3(const int* __restrict__ degi,
                                               const int* __restrict__ boff,
                                               int* __restrict__ rowoff,
                                               int* __restrict__ cur,
                                               float* __restrict__ dis) {
    __shared__ int sums[256];
    int t = threadIdx.x;
    int q = blockIdx.x * 256 + t;
    int d[4] = {0, 0, 0, 0};
    if (q * 4 + 3 < N_NODES) {
        int4 v = reinterpret_cast<const int4*>(degi)[q];
        d[0] = v.x; d[1] = v.y; d[2] = v.z; d[3] = v.w;
    } else {
        for (int j = 0; j < 4; j++)
            if (q * 4 + j < N_NODES) d[j] = degi[q * 4 + j];
    }
    int tsum = d[0] + d[1] + d[2] + d[3];
    sums[t] = tsum;
    __syncthreads();
    for (int off = 1; off < 256; off <<= 1) {
        int v = (t >= off) ? sums[t - off] : 0;
        __syncthreads();
        sums[t] += v;
        __syncthreads();
    }
    int run = boff[blockIdx.x] + sums[t] - tsum;
#pragma unroll
    for (int j = 0; j < 4; j++) {
        int i = q * 4 + j;
        if (i < N_NODES) {
            rowoff[i] = run;
            dis[i] = rsqrtf((float)d[j] + 1.0f);
            cur[i] = 0;
            run += d[j];
            if (i == N_NODES - 1) rowoff[N_NODES] = run;
        }
    }
}

__global__ void k_bucket(const int* __restrict__ src, const int* __restrict__ dst,
                         const int* __restrict__ rowoff, int* __restrict__ cur,
                         int* __restrict__ esrc, int E) {
    int e = blockIdx.x * blockDim.x + threadIdx.x;
    if (e >= E) return;
    int s = src[e], d = dst[e];
    int pos = rowoff[d] + atomicAdd(&cur[d], 1);
    esrc[pos] = s;
}

// W1 [512][96] f32 -> WbT [96][512] bf16 (transposed so B-fragments are k-contiguous)
__global__ __launch_bounds__(256) void k_cvtW(const float* __restrict__ W,
                                              unsigned short* __restrict__ WbT) {
    int idx = blockIdx.x * 256 + threadIdx.x;
    if (idx >= NH * NIN) return;
    int n = idx >> 9;          // 0..95
    int k = idx & 511;
    WbT[idx] = f2bf(W[(size_t)k * NH + n]);
}

// h' = (x @ W1) * dis[row]  via bf16 MFMA 16x16x32. 4 waves x 16 rows = BM 64,
// each wave computes all 96 cols (6 n-tiles). BK=32, 16 iters, reg-prefetch.
// LDS rows are 64 B; XOR key (row&3)<<4 stays IN-ROW (bijective on {0,16,32,48})
// -- round-8's (row&7)<<4 overflowed into the next row and raced.
#define GBM 64
__global__ __launch_bounds__(256) void k_gemm1(const float* __restrict__ x,
                                               const unsigned short* __restrict__ WbT,
                                               const float* __restrict__ dis,
                                               float* __restrict__ hp, int M) {
    __shared__ __align__(16) char lAs[64 * 64];   // 4 KB: row r -> 32 bf16 k
    __shared__ __align__(16) char lBs[96 * 64];   // 6 KB: row n -> 32 bf16 k
    int tid = threadIdx.x;
    int lane = tid & 63;
    int w = tid >> 6;
    int m0 = blockIdx.x * GBM;

    // A-stager: row ar (0..63), chunk ac (8 k each)
    int ar = tid >> 2, ac = tid & 3;
    int agr = min(m0 + ar, M - 1);
    const float* axp = x + (size_t)agr * NIN + ac * 8;
    int aoff = ar * 64 + ((ac * 16) ^ ((ar & 3) << 4));

    // B-stager: row bn (0..95), chunk bc (16 k = 32 B each); threads 192..255 idle
    int bn = tid >> 1, bc = tid & 1;
    bool bact = (bn < NH);
    const unsigned short* bwp = WbT + (size_t)(bact ? bn : 0) * NIN + bc * 16;
    int boff0 = bn * 64 + ((bc * 32 + 0) ^ ((bn & 3) << 4));
    int boff1 = bn * 64 + ((bc * 32 + 16) ^ ((bn & 3) << 4));

    float4 ax0 = *reinterpret_cast<const float4*>(axp);
    float4 ax1 = *reinterpret_cast<const float4*>(axp + 4);
    uint4 bw0 = make_uint4(0, 0, 0, 0), bw1 = make_uint4(0, 0, 0, 0);
    if (bact) {
        bw0 = *reinterpret_cast<const uint4*>(bwp);
        bw1 = *reinterpret_cast<const uint4*>(bwp + 8);
    }

    f32x4 acc[6];
#pragma unroll
    for (int nt = 0; nt < 6; ++nt)
#pragma unroll
        for (int i = 0; i < 4; ++i) acc[nt][i] = 0.f;

    // fragment read addresses (constant over k-loop); row&3 == lane&3
    int xorp = ((lane >> 4) << 4) ^ ((lane & 3) << 4);
    const char* aptr = lAs + (w * 16 + (lane & 15)) * 64 + xorp;
    const char* bptr = lBs + (lane & 15) * 64 + xorp;      // + nt*16*64

    for (int kc = 0; kc < NIN / 32; ++kc) {
        __syncthreads();   // previous tile's readers done
        uint4 ap;
        ap.x = (unsigned)f2bf(ax0.x) | ((unsigned)f2bf(ax0.y) << 16);
        ap.y = (unsigned)f2bf(ax0.z) | ((unsigned)f2bf(ax0.w) << 16);
        ap.z = (unsigned)f2bf(ax1.x) | ((unsigned)f2bf(ax1.y) << 16);
        ap.w = (unsigned)f2bf(ax1.z) | ((unsigned)f2bf(ax1.w) << 16);
        *reinterpret_cast<uint4*>(lAs + aoff) = ap;
        if (bact) {
            *reinterpret_cast<uint4*>(lBs + boff0) = bw0;
            *reinterpret_cast<uint4*>(lBs + boff1) = bw1;
        }
        __syncthreads();   // tile ready

        if (kc + 1 < NIN / 32) {   // issue next tile's global loads
            const float* axn = axp + (kc + 1) * 32;
            ax0 = *reinterpret_cast<const float4*>(axn);
            ax1 = *reinterpret_cast<const float4*>(axn + 4);
            if (bact) {
                const unsigned short* bwn = bwp + (kc + 1) * 32;
                bw0 = *reinterpret_cast<const uint4*>(bwn);
                bw1 = *reinterpret_cast<const uint4*>(bwn + 8);
            }
        }

        short8v a = *reinterpret_cast<const short8v*>(aptr);
#pragma unroll
        for (int nt = 0; nt < 6; ++nt) {
            short8v b = *reinterpret_cast<const short8v*>(bptr + nt * 1024);
            acc[nt] = __builtin_amdgcn_mfma_f32_16x16x32_bf16(a, b, acc[nt], 0, 0, 0);
        }
    }

    // C layout: row=(lane>>4)*4+reg, col=lane&15 (m89-verified); fuse dis scale
    int rbase = m0 + w * 16 + (lane >> 4) * 4;
    int nc = lane & 15;
#pragma unroll
    for (int r = 0; r < 4; ++r) {
        int row = rbase + r;
        if (row < M) {
            float dv = dis[row];
            float* op = hp + (size_t)row * NH + nc;
#pragma unroll
            for (int nt = 0; nt < 6; ++nt) op[nt * 16] = acc[nt][r] * dv;
        }
    }
}

// gather layer 1: hid = relu((sum_{s in N(i)} h'[s] + h'[i]) * dis[i] + b1)
__global__ __launch_bounds__(256) void k_gather1(const float4* __restrict__ h4,
                                                 const int* __restrict__ rowoff,
                                                 const int* __restrict__ esrc,
                                                 const float* __restrict__ dis,
                                                 const float* __restrict__ b1,
                                                 float4* __restrict__ hid4) {
    int tid = threadIdx.x;
    int node = blockIdx.x * 8 + (tid >> 5);
    int c = tid & 31;
    if (node >= N_NODES) return;
    int p0 = rowoff[node], p1 = rowoff[node + 1];
    bool act = (c < NC1);
    float4 acc = make_float4(0.f, 0.f, 0.f, 0.f);
    for (int pb = p0; pb < p1; pb += 32) {
        int nb = min(32, p1 - pb);
        int sv = (c < nb) ? esrc[pb + c] : 0;
#pragma unroll 4
        for (int j = 0; j < nb; j++) {
            int s = __shfl(sv, j, 32);
            if (act) {
                float4 v = h4[(size_t)s * NC1 + c];
                acc.x += v.x; acc.y += v.y; acc.z += v.z; acc.w += v.w;
            }
        }
    }
    if (act) {
        float dv = dis[node];
        float4 hv = h4[(size_t)node * NC1 + c];
        float4 bv = *reinterpret_cast<const float4*>(&b1[c * 4]);
        acc.x = fmaxf((acc.x + hv.x) * dv + bv.x, 0.f);
        acc.y = fmaxf((acc.y + hv.y) * dv + bv.y, 0.f);
        acc.z = fmaxf((acc.z + hv.z) * dv + bv.z, 0.f);
        acc.w = fmaxf((acc.w + hv.w) * dv + bv.w, 0.f);
        hid4[(size_t)node * NC1 + c] = acc;
    }
}

// h23' = (hid @ [W_mu | W_logstd]) * dis[row]
__global__ __launch_bounds__(256) void k_gemm2(const float* __restrict__ hid,
                                               const float* __restrict__ Wmu,
                                               const float* __restrict__ Wls,
                                               const float* __restrict__ dis,
                                               float* __restrict__ h23, int M) {
    __shared__ float wl[NH][NH2];
    int tid = threadIdx.x;
#pragma unroll
    for (int it = 0; it < 6; ++it) {
        int idx = it * 256 + tid;
        int k = idx >> 4;
        int c4 = idx & 15;
        float4 v;
        if (c4 < 8) v = *reinterpret_cast<const float4*>(&Wmu[k * NL + c4 * 4]);
        else        v = *reinterpret_cast<const float4*>(&Wls[k * NL + (c4 - 8) * 4]);
        *reinterpret_cast<float4*>(&wl[k][c4 * 4]) = v;
    }
    __syncthreads();
    int row = blockIdx.x * 128 + (tid >> 1);
    int half = tid & 1;
    if (row >= M) return;
    float acc[NL];
#pragma unroll
    for (int j = 0; j < NL; j++) acc[j] = 0.f;
    const float4* hr4 = reinterpret_cast<const float4*>(&hid[(size_t)row * NH]);
#pragma unroll 6
    for (int kq = 0; kq < NH / 4; kq++) {
        float4 hv = hr4[kq];
        float hvv[4] = {hv.x, hv.y, hv.z, hv.w};
#pragma unroll
        for (int kk = 0; kk < 4; kk++) {
            const float* w = &wl[kq * 4 + kk][half * NL];
#pragma unroll
            for (int j = 0; j < NL; j++) acc[j] = fmaf(hvv[kk], w[j], acc[j]);
        }
    }
    float dv = dis[row];
    float4* o4 = reinterpret_cast<float4*>(&h23[(size_t)row * NH2 + half * NL]);
#pragma unroll
    for (int j4 = 0; j4 < 8; j4++)
        o4[j4] = make_float4(acc[j4 * 4] * dv, acc[j4 * 4 + 1] * dv,
                             acc[j4 * 4 + 2] * dv, acc[j4 * 4 + 3] * dv);
}

// gather layer 2: out = (sum h23'[s] + h23'[i]) * dis[i] + bias, split mu/logstd
__global__ __launch_bounds__(256) void k_gather2(const float4* __restrict__ h23_4,
                                                 const int* __restrict__ rowoff,
                                                 const int* __restrict__ esrc,
                                                 const float* __restrict__ dis,
                                                 const float* __restrict__ bmu,
                                                 const float* __restrict__ bls,
                                                 float4* __restrict__ out4) {
    int tid = threadIdx.x;
    int node = blockIdx.x * 16 + (tid >> 4);
    int c = tid & 15;
    if (node >= N_NODES) return;
    int p0 = rowoff[node], p1 = rowoff[node + 1];
    float4 acc = make_float4(0.f, 0.f, 0.f, 0.f);
    for (int pb = p0; pb < p1; pb += 16) {
        int nb = min(16, p1 - pb);
        int sv = (c < nb) ? esrc[pb + c] : 0;
#pragma unroll 4
        for (int j = 0; j < nb; j++) {
            int s = __shfl(sv, j, 16);
            float4 v = h23_4[(size_t)s * NC2 + c];
            acc.x += v.x; acc.y += v.y; acc.z += v.z; acc.w += v.w;
        }
    }
    float dv = dis[node];
    float4 hv = h23_4[(size_t)node * NC2 + c];
    float4 bv = (c < 8) ? reinterpret_cast<const float4*>(bmu)[c]
                        : reinterpret_cast<const float4*>(bls)[c - 8];
    acc.x = (acc.x + hv.x) * dv + bv.x;
    acc.y = (acc.y + hv.y) * dv + bv.y;
    acc.z = (acc.z + hv.z) * dv + bv.z;
    acc.w = (acc.w + hv.w) * dv + bv.w;
    if (c < 8) out4[(size_t)node * 8 + c] = acc;
    else       out4[(size_t)N_NODES * 8 + (size_t)node * 8 + (c - 8)] = acc;
}

extern "C" void kernel_launch(void* const* d_in, const int* in_sizes, int n_in,
                              void* d_out, int out_size, void* d_ws, size_t ws_size,
                              hipStream_t stream) {
    const float* x   = (const float*)d_in[0];
    const float* W1  = (const float*)d_in[1];
    const float* b1  = (const float*)d_in[2];
    const float* Wmu = (const float*)d_in[3];
    const float* bmu = (const float*)d_in[4];
    const float* Wls = (const float*)d_in[5];
    const float* bls = (const float*)d_in[6];
    const int*   ei  = (const int*)d_in[7];
    int E = in_sizes[7] / 2;
    const int* src  = ei;
    const int* dstp = ei + E;

    char* w = (char*)d_ws;
    int* degi    = (int*)w;            w += (size_t)N_NODES * 4;
    int* cur     = (int*)w;            w += (size_t)N_NODES * 4;
    int* rowoff  = (int*)w;            w += ((size_t)N_NODES + 4) * 4;
    float* dis   = (float*)w;          w += (size_t)N_NODES * 4;
    int* bsum    = (int*)w;            w += 64 * 4;
    int* boff    = (int*)w;            w += 64 * 4;
    int* esrc    = (int*)w;            w += (size_t)E * 4;
    unsigned short* WbT = (unsigned short*)w;  w += (size_t)NH * NIN * 2;
    float* hprim = (float*)w;          w += (size_t)N_NODES * NH * 4;
    float* hid   = (float*)w;          w += (size_t)N_NODES * NH * 4;
    float* h23   = (float*)w;          w += (size_t)N_NODES * NH2 * 4;

    k_cvtW<<<(NH * NIN + 255) / 256, 256, 0, stream>>>(W1, WbT);

    k_zero_int<<<(N_NODES + 255) / 256, 256, 0, stream>>>(degi, N_NODES);
    k_degi<<<(E + 255) / 256, 256, 0, stream>>>(dstp, degi, E);
    k_scan1<<<SCAN_BLK, 256, 0, stream>>>(degi, bsum);
    k_scan2<<<1, 64, 0, stream>>>(bsum, boff);
    k_scan3<<<SCAN_BLK, 256, 0, stream>>>(degi, boff, rowoff, cur, dis);
    k_bucket<<<(E + 255) / 256, 256, 0, stream>>>(src, dstp, rowoff, cur, esrc, E);

    k_gemm1<<<(N_NODES + GBM - 1) / GBM, 256, 0, stream>>>(x, WbT, dis, hprim, N_NODES);

    k_gather1<<<(N_NODES + 7) / 8, 256, 0, stream>>>(
        (const float4*)hprim, rowoff, esrc, dis, b1, (float4*)hid);

    k_gemm2<<<(N_NODES + 127) / 128, 256, 0, stream>>>(hid, Wmu, Wls, dis, h23, N_NODES);

    k_gather2<<<(N_NODES + 15) / 16, 256, 0, stream>>>(
        (const float4*)h23, rowoff, esrc, dis, bmu, bls, (float4*)d_out);
}